// Round 7
// baseline (814.145 us; speedup 1.0000x reference)
//
#include <hip/hip_runtime.h>
#include <hip/hip_bf16.h>

#define TPB 256
#define SCAN_T 256
#define SCAN_E 2048   // elements scanned per block (8 per thread)
#define EDGE_B 8      // edges per thread in hist/scatter (ILP)

typedef __attribute__((ext_vector_type(8))) short bf16x8;
typedef __attribute__((ext_vector_type(4))) float f32x4;

// permuted layout: p = h*16 + d  <->  original o = d*8 + h
__device__ __forceinline__ int origcol(int p) { return ((p & 15) << 3) + (p >> 4); }

// fp32 -> bf16 round-to-nearest-even
__device__ __forceinline__ unsigned short f2bf(float f) {
    unsigned int u = __float_as_uint(f);
    u += 0x7fffu + ((u >> 16) & 1u);
    return (unsigned short)(u >> 16);
}
__device__ __forceinline__ float bf2f_lo(unsigned int w) { return __uint_as_float(w << 16); }
__device__ __forceinline__ float bf2f_hi(unsigned int w) { return __uint_as_float(w & 0xffff0000u); }

// ---------------------------------------------------------------------------
// Q/K/V projection via bf16 MFMA, NO LDS, NO barriers, NO prep: B-fragments
// load fp32 W rows (head-major row = origcol(p)) straight from global and
// convert in-registers. Per wave: 16 nodes x 384 outputs.
// q head-major; k,v interleaved into kv[node*256 + head*32 + d] (k) / +16 (v).
// ---------------------------------------------------------------------------
__global__ __launch_bounds__(256) void proj_kernel(
    const float* __restrict__ h,
    const float* __restrict__ Wq, const float* __restrict__ bq,
    const float* __restrict__ Wk, const float* __restrict__ bk,
    const float* __restrict__ Wv, const float* __restrict__ bv,
    unsigned short* __restrict__ qo, unsigned short* __restrict__ kv, int n)
{
    const int tid  = threadIdx.x;
    const int nb   = blockIdx.x * 64;
    const int wv   = tid >> 6;
    const int lane = tid & 63;
    const int jj   = lane & 15;
    const int g    = lane >> 4;

    // A fragments: node = nb + wv*16 + jj, 8 consecutive k at kk*32 + g*8
    const int node_a = nb + wv * 16 + jj;
    bf16x8 afrag[4];
    #pragma unroll
    for (int kk = 0; kk < 4; ++kk) {
        float fv[8];
        if (node_a < n) {
            const float4* src = (const float4*)(h + (size_t)node_a * 128 + kk * 32 + g * 8);
            float4 x0 = src[0], x1 = src[1];
            fv[0] = x0.x; fv[1] = x0.y; fv[2] = x0.z; fv[3] = x0.w;
            fv[4] = x1.x; fv[5] = x1.y; fv[6] = x1.z; fv[7] = x1.w;
        } else {
            #pragma unroll
            for (int i = 0; i < 8; ++i) fv[i] = 0.f;
        }
        bf16x8 a;
        #pragma unroll
        for (int i = 0; i < 8; ++i) a[i] = (short)f2bf(fv[i]);
        afrag[kk] = a;
    }

    #pragma unroll 1
    for (int mat = 0; mat < 3; ++mat) {
        const float* W    = (mat == 0) ? Wq : ((mat == 1) ? Wk : Wv);
        const float* bias = (mat == 0) ? bq : ((mat == 1) ? bk : bv);

        f32x4 acc[8];
        #pragma unroll
        for (int ct = 0; ct < 8; ++ct) { f32x4 z = {0.f, 0.f, 0.f, 0.f}; acc[ct] = z; }

        #pragma unroll
        for (int kk = 0; kk < 4; ++kk) {
            #pragma unroll
            for (int ct = 0; ct < 8; ++ct) {
                const float4* wp = (const float4*)(W + (size_t)origcol(ct * 16 + jj) * 128
                                                     + kk * 32 + g * 8);
                float4 w0 = wp[0], w1 = wp[1];
                bf16x8 b;
                b[0] = (short)f2bf(w0.x); b[1] = (short)f2bf(w0.y);
                b[2] = (short)f2bf(w0.z); b[3] = (short)f2bf(w0.w);
                b[4] = (short)f2bf(w1.x); b[5] = (short)f2bf(w1.y);
                b[6] = (short)f2bf(w1.z); b[7] = (short)f2bf(w1.w);
                acc[ct] = __builtin_amdgcn_mfma_f32_16x16x32_bf16(afrag[kk], b, acc[ct], 0, 0, 0);
            }
        }

        const float scale = (mat == 0) ? 0.25f : 1.0f;   // D^-0.5 on q
        #pragma unroll
        for (int ct = 0; ct < 8; ++ct) {
            int p = ct * 16 + jj;
            float bsv = bias[origcol(p)];
            #pragma unroll
            for (int r = 0; r < 4; ++r) {
                int node = nb + wv * 16 + g * 4 + r;
                if (node < n) {
                    unsigned short val = f2bf((acc[ct][r] + bsv) * scale);
                    if (mat == 0)
                        qo[(size_t)node * 128 + p] = val;
                    else {
                        size_t addr = (size_t)node * 256 + ((p >> 4) << 5) + (p & 15)
                                      + ((mat == 2) ? 16 : 0);
                        kv[addr] = val;
                    }
                }
            }
        }
    }
}

// ---------------------------------------------------------------------------
// Standalone edge histogram, 8 edges/thread ILP.
// ---------------------------------------------------------------------------
__global__ __launch_bounds__(256) void hist_kernel(
    const int* __restrict__ row, int* __restrict__ cnt, int E)
{
    int t = blockIdx.x * TPB + threadIdx.x;
    int base = t * EDGE_B;
    if (base >= E) return;
    if (base + EDGE_B <= E) {
        int4 r0 = *(const int4*)(row + base);
        int4 r1 = *(const int4*)(row + base + 4);
        atomicAdd(&cnt[r0.x], 1); atomicAdd(&cnt[r0.y], 1);
        atomicAdd(&cnt[r0.z], 1); atomicAdd(&cnt[r0.w], 1);
        atomicAdd(&cnt[r1.x], 1); atomicAdd(&cnt[r1.y], 1);
        atomicAdd(&cnt[r1.z], 1); atomicAdd(&cnt[r1.w], 1);
    } else {
        for (int i = base; i < E; ++i) atomicAdd(&cnt[row[i]], 1);
    }
}

// ---------------------------------------------------------------------------
// CSR scans
// ---------------------------------------------------------------------------
__global__ __launch_bounds__(SCAN_T) void scan1_kernel(
    const int* __restrict__ cnt, int* __restrict__ excl, int* __restrict__ btot, int n)
{
    __shared__ int sd[SCAN_T];
    int t = threadIdx.x, b = blockIdx.x;
    int base = b * SCAN_E + t * 8;
    int vals[8]; int sum = 0;
    #pragma unroll
    for (int i = 0; i < 8; ++i) {
        int idx = base + i;
        vals[i] = (idx < n) ? cnt[idx] : 0;
        sum += vals[i];
    }
    sd[t] = sum;
    __syncthreads();
    for (int off = 1; off < SCAN_T; off <<= 1) {
        int x = (t >= off) ? sd[t - off] : 0;
        __syncthreads();
        sd[t] += x;
        __syncthreads();
    }
    int run = sd[t] - sum;
    #pragma unroll
    for (int i = 0; i < 8; ++i) {
        int idx = base + i;
        if (idx < n) excl[idx] = run;
        run += vals[i];
    }
    if (t == SCAN_T - 1) btot[b] = sd[t];
}

__global__ __launch_bounds__(SCAN_T) void scan2_kernel(int* __restrict__ btot, int nb)
{
    __shared__ int sd[SCAN_T];
    int t = threadIdx.x;
    int orig = (t < nb) ? btot[t] : 0;
    sd[t] = orig;
    __syncthreads();
    for (int off = 1; off < SCAN_T; off <<= 1) {
        int x = (t >= off) ? sd[t - off] : 0;
        __syncthreads();
        sd[t] += x;
        __syncthreads();
    }
    if (t < nb) btot[t] = sd[t] - orig;
}

__global__ __launch_bounds__(SCAN_T) void scan3_kernel(
    int* __restrict__ roff, int* __restrict__ cur, const int* __restrict__ btot, int n)
{
    int add = btot[blockIdx.x];
    int base = blockIdx.x * SCAN_E + threadIdx.x;
    #pragma unroll
    for (int i = 0; i < 8; ++i) {
        int idx = base + i * SCAN_T;
        if (idx < n) { int val = roff[idx] + add; roff[idx] = val; cur[idx] = val; }
    }
}

// ---------------------------------------------------------------------------
// Scatter with 8 edges/thread ILP: 8 independent atomicAdds in flight.
// ---------------------------------------------------------------------------
__global__ __launch_bounds__(256) void scatter_kernel(
    const int* __restrict__ row, const int* __restrict__ col,
    int* __restrict__ cur, int* __restrict__ ecol, int E)
{
    int t = blockIdx.x * TPB + threadIdx.x;
    int base = t * EDGE_B;
    if (base >= E) return;
    if (base + EDGE_B <= E) {
        int4 r0 = *(const int4*)(row + base);
        int4 r1 = *(const int4*)(row + base + 4);
        int4 c0 = *(const int4*)(col + base);
        int4 c1 = *(const int4*)(col + base + 4);
        int rr[8] = {r0.x, r0.y, r0.z, r0.w, r1.x, r1.y, r1.z, r1.w};
        int cc[8] = {c0.x, c0.y, c0.z, c0.w, c1.x, c1.y, c1.z, c1.w};
        int pos[8];
        #pragma unroll
        for (int i = 0; i < 8; ++i) pos[i] = atomicAdd(&cur[rr[i]], 1);
        #pragma unroll
        for (int i = 0; i < 8; ++i) ecol[pos[i]] = cc[i];
    } else {
        for (int i = base; i < E; ++i) {
            int pos = atomicAdd(&cur[row[i]], 1);
            ecol[pos] = col[i];
        }
    }
}

// ---------------------------------------------------------------------------
// Fused attention, bf16, interleaved kv. One wave per dest node, lane = j*8+h.
// Per (edge, head): one contiguous 64B read (k:32B | v:32B).
// ao aliases q (wave reads q[i] into regs before storing ao[i]).
// ---------------------------------------------------------------------------
__global__ __launch_bounds__(256) void attn_kernel(
    const unsigned short* q, const unsigned short* __restrict__ kv,
    const int* __restrict__ roff, const int* __restrict__ cnt,
    const int* __restrict__ ecol, unsigned short* ao, int n)
{
    int wave = threadIdx.x >> 6;
    int lane = threadIdx.x & 63;
    int i = blockIdx.x * 4 + wave;
    if (i >= n) return;
    int hh = lane & 7;
    int j  = lane >> 3;

    float qf[16];
    {
        const uint4* qp = (const uint4*)(q + (size_t)i * 128 + hh * 16);
        uint4 a = qp[0], b = qp[1];
        qf[0] = bf2f_lo(a.x);  qf[1] = bf2f_hi(a.x);  qf[2]  = bf2f_lo(a.y);  qf[3]  = bf2f_hi(a.y);
        qf[4] = bf2f_lo(a.z);  qf[5] = bf2f_hi(a.z);  qf[6]  = bf2f_lo(a.w);  qf[7]  = bf2f_hi(a.w);
        qf[8] = bf2f_lo(b.x);  qf[9] = bf2f_hi(b.x);  qf[10] = bf2f_lo(b.y);  qf[11] = bf2f_hi(b.y);
        qf[12]= bf2f_lo(b.z);  qf[13]= bf2f_hi(b.z);  qf[14] = bf2f_lo(b.w);  qf[15] = bf2f_hi(b.w);
    }

    float s = 0.f;
    float acc[16];
    #pragma unroll
    for (int d = 0; d < 16; ++d) acc[d] = 0.f;

    int start = roff[i];
    int end   = start + cnt[i];
    for (int p = start + j; p < end; p += 8) {
        int c = ecol[p];
        const uint4* kp = (const uint4*)(kv + (size_t)c * 256 + hh * 32);
        uint4 ka = kp[0], kb = kp[1];   // k fragment (32B)
        uint4 va = kp[2], vb = kp[3];   // v fragment (32B), same 64B line
        float dot;
        dot = qf[0] * bf2f_lo(ka.x);
        dot = fmaf(qf[1],  bf2f_hi(ka.x), dot); dot = fmaf(qf[2],  bf2f_lo(ka.y), dot);
        dot = fmaf(qf[3],  bf2f_hi(ka.y), dot); dot = fmaf(qf[4],  bf2f_lo(ka.z), dot);
        dot = fmaf(qf[5],  bf2f_hi(ka.z), dot); dot = fmaf(qf[6],  bf2f_lo(ka.w), dot);
        dot = fmaf(qf[7],  bf2f_hi(ka.w), dot); dot = fmaf(qf[8],  bf2f_lo(kb.x), dot);
        dot = fmaf(qf[9],  bf2f_hi(kb.x), dot); dot = fmaf(qf[10], bf2f_lo(kb.y), dot);
        dot = fmaf(qf[11], bf2f_hi(kb.y), dot); dot = fmaf(qf[12], bf2f_lo(kb.z), dot);
        dot = fmaf(qf[13], bf2f_hi(kb.z), dot); dot = fmaf(qf[14], bf2f_lo(kb.w), dot);
        dot = fmaf(qf[15], bf2f_hi(kb.w), dot);
        float ev = __expf(dot);
        s += ev;
        acc[0]  = fmaf(ev, bf2f_lo(va.x), acc[0]);  acc[1]  = fmaf(ev, bf2f_hi(va.x), acc[1]);
        acc[2]  = fmaf(ev, bf2f_lo(va.y), acc[2]);  acc[3]  = fmaf(ev, bf2f_hi(va.y), acc[3]);
        acc[4]  = fmaf(ev, bf2f_lo(va.z), acc[4]);  acc[5]  = fmaf(ev, bf2f_hi(va.z), acc[5]);
        acc[6]  = fmaf(ev, bf2f_lo(va.w), acc[6]);  acc[7]  = fmaf(ev, bf2f_hi(va.w), acc[7]);
        acc[8]  = fmaf(ev, bf2f_lo(vb.x), acc[8]);  acc[9]  = fmaf(ev, bf2f_hi(vb.x), acc[9]);
        acc[10] = fmaf(ev, bf2f_lo(vb.y), acc[10]); acc[11] = fmaf(ev, bf2f_hi(vb.y), acc[11]);
        acc[12] = fmaf(ev, bf2f_lo(vb.z), acc[12]); acc[13] = fmaf(ev, bf2f_hi(vb.z), acc[13]);
        acc[14] = fmaf(ev, bf2f_lo(vb.w), acc[14]); acc[15] = fmaf(ev, bf2f_hi(vb.w), acc[15]);
    }

    #pragma unroll
    for (int m = 8; m <= 32; m <<= 1) {
        s += __shfl_xor(s, m);
        #pragma unroll
        for (int d = 0; d < 16; ++d) acc[d] += __shfl_xor(acc[d], m);
    }

    if (j == 0) {
        float inv = (s > 0.f) ? 1.f / s : 0.f;
        unsigned int w[8];
        #pragma unroll
        for (int d = 0; d < 8; ++d)
            w[d] = (unsigned int)f2bf(acc[2 * d] * inv) |
                   ((unsigned int)f2bf(acc[2 * d + 1] * inv) << 16);
        uint4* op = (uint4*)(ao + (size_t)i * 128 + hh * 16);
        op[0] = make_uint4(w[0], w[1], w[2], w[3]);
        op[1] = make_uint4(w[4], w[5], w[6], w[7]);
    }
}

// ---------------------------------------------------------------------------
// Output projection via bf16 MFMA, NO LDS, NO prep: out = ao @ Wo^T + bo.
// ao is head-major, so the K-index permutation is applied to Wo's columns at
// load time: frag elem i = Wo[row][ (d0+i)*8 + h0 ] (stride-8 scalar loads,
// Wo is 64 KB -> L1/L2-resident).
// ---------------------------------------------------------------------------
__global__ __launch_bounds__(256) void outproj_kernel(
    const unsigned short* __restrict__ ao, const float* __restrict__ Wo,
    const float* __restrict__ bo, float* __restrict__ out, int n)
{
    const int tid  = threadIdx.x;
    const int nb   = blockIdx.x * 64;
    const int wv   = tid >> 6;
    const int lane = tid & 63;
    const int jj   = lane & 15;
    const int g    = lane >> 4;

    const int node_a = nb + wv * 16 + jj;
    bf16x8 afrag[4];
    #pragma unroll
    for (int kk = 0; kk < 4; ++kk) {
        if (node_a < n)
            afrag[kk] = *(const bf16x8*)(ao + (size_t)node_a * 128 + kk * 32 + g * 8);
        else {
            bf16x8 z;
            #pragma unroll
            for (int i = 0; i < 8; ++i) z[i] = 0;
            afrag[kk] = z;
        }
    }

    f32x4 acc[8];
    #pragma unroll
    for (int ct = 0; ct < 8; ++ct) { f32x4 z = {0.f, 0.f, 0.f, 0.f}; acc[ct] = z; }

    #pragma unroll
    for (int kk = 0; kk < 4; ++kk) {
        const int k0 = kk * 32 + g * 8;                 // head-major k base
        const int woff = ((k0 & 15) << 3) + (k0 >> 4);  // origcol(k0)
        #pragma unroll
        for (int ct = 0; ct < 8; ++ct) {
            const float* wrow = Wo + (size_t)(ct * 16 + jj) * 128 + woff;
            bf16x8 b;
            #pragma unroll
            for (int i = 0; i < 8; ++i) b[i] = (short)f2bf(wrow[i * 8]);
            acc[ct] = __builtin_amdgcn_mfma_f32_16x16x32_bf16(afrag[kk], b, acc[ct], 0, 0, 0);
        }
    }

    #pragma unroll
    for (int ct = 0; ct < 8; ++ct) {
        int jr = ct * 16 + jj;
        float bsv = bo[jr];
        #pragma unroll
        for (int r = 0; r < 4; ++r) {
            int node = nb + wv * 16 + g * 4 + r;
            if (node < n)
                out[(size_t)node * 128 + jr] = acc[ct][r] + bsv;
        }
    }
}

// ---------------------------------------------------------------------------

extern "C" void kernel_launch(void* const* d_in, const int* in_sizes, int n_in,
                              void* d_out, int out_size, void* d_ws, size_t ws_size,
                              hipStream_t stream)
{
    const float* h   = (const float*)d_in[0];
    const int*   row = (const int*)d_in[1];
    const int*   col = (const int*)d_in[2];
    const float* Wq  = (const float*)d_in[3];
    const float* bq  = (const float*)d_in[4];
    const float* Wk  = (const float*)d_in[5];
    const float* bk  = (const float*)d_in[6];
    const float* Wv  = (const float*)d_in[7];
    const float* bv  = (const float*)d_in[8];
    const float* Wo  = (const float*)d_in[9];
    const float* bo  = (const float*)d_in[10];

    const int n = in_sizes[0] / 128;
    const int E = in_sizes[1];
    float* out = (float*)d_out;

    // workspace layout
    char* ws = (char*)d_ws;
    unsigned short* q  = (unsigned short*)ws; ws += (size_t)n * 128 * sizeof(unsigned short);
    unsigned short* kv = (unsigned short*)ws; ws += (size_t)n * 256 * sizeof(unsigned short);
    int* cnt  = (int*)ws; ws += (size_t)n * sizeof(int);
    int* roff = (int*)ws; ws += (size_t)n * sizeof(int);
    int* cur  = (int*)ws; ws += (size_t)n * sizeof(int);
    int* ecol = (int*)ws; ws += (size_t)E * sizeof(int);
    int* btot = (int*)ws; ws += 256 * sizeof(int);
    unsigned short* ao = q;   // alias: attn reads q[i] into regs before storing ao[i]
    if (ws_size < (size_t)(ws - (char*)d_ws)) return;

    (void)hipMemsetAsync(cnt, 0, (size_t)n * sizeof(int), stream);

    int eblocks = (E + TPB * EDGE_B - 1) / (TPB * EDGE_B);
    hist_kernel<<<eblocks, TPB, 0, stream>>>(row, cnt, E);

    proj_kernel<<<(n + 63) / 64, TPB, 0, stream>>>(h, Wq, bq, Wk, bk, Wv, bv, q, kv, n);

    int nsb = (n + SCAN_E - 1) / SCAN_E;   // 49 for n=100k (<= 256)
    scan1_kernel<<<nsb, SCAN_T, 0, stream>>>(cnt, roff, btot, n);
    scan2_kernel<<<1, SCAN_T, 0, stream>>>(btot, nsb);
    scan3_kernel<<<nsb, SCAN_T, 0, stream>>>(roff, cur, btot, n);

    scatter_kernel<<<eblocks, TPB, 0, stream>>>(row, col, cur, ecol, E);

    attn_kernel<<<(n + 3) / 4, TPB, 0, stream>>>(q, kv, roff, cnt, ecol, ao, n);

    outproj_kernel<<<(n + 63) / 64, TPB, 0, stream>>>(ao, Wo, bo, out, n);
}

// Round 8
// 550.251 us; speedup vs baseline: 1.4796x; 1.4796x over previous
//
#include <hip/hip_runtime.h>
#include <hip/hip_bf16.h>

#define TPB 256
#define SCAN_T 256
#define SCAN_E 2048   // elements scanned per block (8 per thread)
#define EDGE_B 8      // edges per thread in scatter (ILP)

typedef __attribute__((ext_vector_type(8))) short bf16x8;
typedef __attribute__((ext_vector_type(4))) float f32x4;

// permuted layout: p = h*16 + d  <->  original o = d*8 + h
__device__ __forceinline__ int origcol(int p) { return ((p & 15) << 3) + (p >> 4); }

// fp32 -> bf16 round-to-nearest-even
__device__ __forceinline__ unsigned short f2bf(float f) {
    unsigned int u = __float_as_uint(f);
    u += 0x7fffu + ((u >> 16) & 1u);
    return (unsigned short)(u >> 16);
}
__device__ __forceinline__ float bf2f_lo(unsigned int w) { return __uint_as_float(w << 16); }
__device__ __forceinline__ float bf2f_hi(unsigned int w) { return __uint_as_float(w & 0xffff0000u); }

// ---------------------------------------------------------------------------
// One-time weight prep: Wq/Wk/Wv -> bf16, rows permuted to head-major
// (wbf[mat][p][k] = W[origcol(p)][k]); Wo -> bf16 with K-columns permuted
// (wobf[j][c] = Wo[j][origcol(c)]); permuted qkv biases.
// R6 BUG FIXED HERE: bias staging must be a strided loop (384 > 256 threads);
// the `if (t < 384)` form left bp[256..383] (the V bias) as 0xAA poison.
// ---------------------------------------------------------------------------
__global__ __launch_bounds__(256) void prep_kernel(
    const float* __restrict__ Wq, const float* __restrict__ Wk,
    const float* __restrict__ Wv, const float* __restrict__ Wo,
    const float* __restrict__ bq, const float* __restrict__ bk,
    const float* __restrict__ bv,
    unsigned short* __restrict__ wbf, unsigned short* __restrict__ wobf,
    float* __restrict__ bp)
{
    int b = blockIdx.x;
    if (b == 256) {
        for (int t = threadIdx.x; t < 384; t += 256) {
            const float* bsrc = (t < 128) ? bq : ((t < 256) ? bk : bv);
            bp[t] = bsrc[origcol(t & 127)];
        }
        return;
    }
    int gid = b * 256 + threadIdx.x;   // 0..65535
    int mat = gid >> 14;
    int rem = gid & 16383;
    int p = rem >> 7, k = rem & 127;
    if (mat < 3) {
        const float* W = (mat == 0) ? Wq : ((mat == 1) ? Wk : Wv);
        wbf[gid] = f2bf(W[(size_t)origcol(p) * 128 + k]);
    } else {
        wobf[p * 128 + k] = f2bf(Wo[(size_t)p * 128 + origcol(k)]);
    }
}

// ---------------------------------------------------------------------------
// Q/K/V projection via bf16 MFMA, NO LDS, NO barriers. B-fragments read
// directly from prepped global bf16 W (L1/L2-resident). Embedded edge
// histogram: fire-and-forget atomics. Per wave: 16 nodes x 384 outputs.
// q head-major; k,v interleaved into kv[node*256 + head*32 + d] (k) / +16 (v).
// ---------------------------------------------------------------------------
__global__ __launch_bounds__(256) void proj_kernel(
    const float* __restrict__ h,
    const unsigned short* __restrict__ wbf, const float* __restrict__ bp,
    unsigned short* __restrict__ qo, unsigned short* __restrict__ kv,
    int n,
    const int* __restrict__ row, int* __restrict__ cnt, int E, int ept)
{
    const int tid  = threadIdx.x;
    const int gtid = blockIdx.x * TPB + tid;

    // ---- embedded histogram ----
    {
        long base = (long)gtid * ept;
        if (base < E) {
            if (ept == 4 && base + 4 <= (long)E) {
                int4 r0 = *(const int4*)(row + base);
                atomicAdd(&cnt[r0.x], 1); atomicAdd(&cnt[r0.y], 1);
                atomicAdd(&cnt[r0.z], 1); atomicAdd(&cnt[r0.w], 1);
            } else {
                long lim = base + ept; if (lim > E) lim = E;
                for (long i = base; i < lim; ++i) atomicAdd(&cnt[row[i]], 1);
            }
        }
    }

    const int nb   = blockIdx.x * 64;
    const int wv   = tid >> 6;
    const int lane = tid & 63;
    const int jj   = lane & 15;
    const int g    = lane >> 4;

    // A fragments: node = nb + wv*16 + jj, 8 consecutive k at kk*32 + g*8
    const int node_a = nb + wv * 16 + jj;
    bf16x8 afrag[4];
    #pragma unroll
    for (int kk = 0; kk < 4; ++kk) {
        float fv[8];
        if (node_a < n) {
            const float4* src = (const float4*)(h + (size_t)node_a * 128 + kk * 32 + g * 8);
            float4 x0 = src[0], x1 = src[1];
            fv[0] = x0.x; fv[1] = x0.y; fv[2] = x0.z; fv[3] = x0.w;
            fv[4] = x1.x; fv[5] = x1.y; fv[6] = x1.z; fv[7] = x1.w;
        } else {
            #pragma unroll
            for (int i = 0; i < 8; ++i) fv[i] = 0.f;
        }
        bf16x8 a;
        #pragma unroll
        for (int i = 0; i < 8; ++i) a[i] = (short)f2bf(fv[i]);
        afrag[kk] = a;
    }

    #pragma unroll 1
    for (int mat = 0; mat < 3; ++mat) {
        const unsigned short* wm = wbf + mat * 16384;
        f32x4 acc[8];
        #pragma unroll
        for (int ct = 0; ct < 8; ++ct) { f32x4 z = {0.f, 0.f, 0.f, 0.f}; acc[ct] = z; }

        #pragma unroll
        for (int kk = 0; kk < 4; ++kk) {
            #pragma unroll
            for (int ct = 0; ct < 8; ++ct) {
                bf16x8 b = *(const bf16x8*)(wm + (ct * 16 + jj) * 128 + kk * 32 + g * 8);
                acc[ct] = __builtin_amdgcn_mfma_f32_16x16x32_bf16(afrag[kk], b, acc[ct], 0, 0, 0);
            }
        }

        const float scale = (mat == 0) ? 0.25f : 1.0f;   // D^-0.5 on q
        #pragma unroll
        for (int ct = 0; ct < 8; ++ct) {
            int p = ct * 16 + jj;
            float bsv = bp[mat * 128 + p];
            #pragma unroll
            for (int r = 0; r < 4; ++r) {
                int node = nb + wv * 16 + g * 4 + r;
                if (node < n) {
                    unsigned short val = f2bf((acc[ct][r] + bsv) * scale);
                    if (mat == 0)
                        qo[(size_t)node * 128 + p] = val;
                    else {
                        size_t addr = (size_t)node * 256 + ((p >> 4) << 5) + (p & 15)
                                      + ((mat == 2) ? 16 : 0);
                        kv[addr] = val;
                    }
                }
            }
        }
    }
}

// ---------------------------------------------------------------------------
// CSR scans
// ---------------------------------------------------------------------------
__global__ __launch_bounds__(SCAN_T) void scan1_kernel(
    const int* __restrict__ cnt, int* __restrict__ excl, int* __restrict__ btot, int n)
{
    __shared__ int sd[SCAN_T];
    int t = threadIdx.x, b = blockIdx.x;
    int base = b * SCAN_E + t * 8;
    int vals[8]; int sum = 0;
    #pragma unroll
    for (int i = 0; i < 8; ++i) {
        int idx = base + i;
        vals[i] = (idx < n) ? cnt[idx] : 0;
        sum += vals[i];
    }
    sd[t] = sum;
    __syncthreads();
    for (int off = 1; off < SCAN_T; off <<= 1) {
        int x = (t >= off) ? sd[t - off] : 0;
        __syncthreads();
        sd[t] += x;
        __syncthreads();
    }
    int run = sd[t] - sum;
    #pragma unroll
    for (int i = 0; i < 8; ++i) {
        int idx = base + i;
        if (idx < n) excl[idx] = run;
        run += vals[i];
    }
    if (t == SCAN_T - 1) btot[b] = sd[t];
}

__global__ __launch_bounds__(SCAN_T) void scan2_kernel(int* __restrict__ btot, int nb)
{
    __shared__ int sd[SCAN_T];
    int t = threadIdx.x;
    int orig = (t < nb) ? btot[t] : 0;
    sd[t] = orig;
    __syncthreads();
    for (int off = 1; off < SCAN_T; off <<= 1) {
        int x = (t >= off) ? sd[t - off] : 0;
        __syncthreads();
        sd[t] += x;
        __syncthreads();
    }
    if (t < nb) btot[t] = sd[t] - orig;
}

__global__ __launch_bounds__(SCAN_T) void scan3_kernel(
    int* __restrict__ roff, int* __restrict__ cur, const int* __restrict__ btot, int n)
{
    int add = btot[blockIdx.x];
    int base = blockIdx.x * SCAN_E + threadIdx.x;
    #pragma unroll
    for (int i = 0; i < 8; ++i) {
        int idx = base + i * SCAN_T;
        if (idx < n) { int val = roff[idx] + add; roff[idx] = val; cur[idx] = val; }
    }
}

// ---------------------------------------------------------------------------
// Scatter with 8 edges/thread ILP: 8 independent atomicAdds in flight.
// ---------------------------------------------------------------------------
__global__ __launch_bounds__(256) void scatter_kernel(
    const int* __restrict__ row, const int* __restrict__ col,
    int* __restrict__ cur, int* __restrict__ ecol, int E)
{
    int t = blockIdx.x * TPB + threadIdx.x;
    int base = t * EDGE_B;
    if (base >= E) return;
    if (base + EDGE_B <= E) {
        int4 r0 = *(const int4*)(row + base);
        int4 r1 = *(const int4*)(row + base + 4);
        int4 c0 = *(const int4*)(col + base);
        int4 c1 = *(const int4*)(col + base + 4);
        int rr[8] = {r0.x, r0.y, r0.z, r0.w, r1.x, r1.y, r1.z, r1.w};
        int cc[8] = {c0.x, c0.y, c0.z, c0.w, c1.x, c1.y, c1.z, c1.w};
        int pos[8];
        #pragma unroll
        for (int i = 0; i < 8; ++i) pos[i] = atomicAdd(&cur[rr[i]], 1);
        #pragma unroll
        for (int i = 0; i < 8; ++i) ecol[pos[i]] = cc[i];
    } else {
        for (int i = base; i < E; ++i) {
            int pos = atomicAdd(&cur[row[i]], 1);
            ecol[pos] = col[i];
        }
    }
}

// ---------------------------------------------------------------------------
// Fused attention, bf16, interleaved kv. One wave per dest node, lane = j*8+h.
// Per (edge, head): one contiguous 64B read (k:32B | v:32B).
// ao aliases q (wave reads q[i] into regs before storing ao[i]).
// ---------------------------------------------------------------------------
__global__ __launch_bounds__(256) void attn_kernel(
    const unsigned short* q, const unsigned short* __restrict__ kv,
    const int* __restrict__ roff, const int* __restrict__ cnt,
    const int* __restrict__ ecol, unsigned short* ao, int n)
{
    int wave = threadIdx.x >> 6;
    int lane = threadIdx.x & 63;
    int i = blockIdx.x * 4 + wave;
    if (i >= n) return;
    int hh = lane & 7;
    int j  = lane >> 3;

    float qf[16];
    {
        const uint4* qp = (const uint4*)(q + (size_t)i * 128 + hh * 16);
        uint4 a = qp[0], b = qp[1];
        qf[0] = bf2f_lo(a.x);  qf[1] = bf2f_hi(a.x);  qf[2]  = bf2f_lo(a.y);  qf[3]  = bf2f_hi(a.y);
        qf[4] = bf2f_lo(a.z);  qf[5] = bf2f_hi(a.z);  qf[6]  = bf2f_lo(a.w);  qf[7]  = bf2f_hi(a.w);
        qf[8] = bf2f_lo(b.x);  qf[9] = bf2f_hi(b.x);  qf[10] = bf2f_lo(b.y);  qf[11] = bf2f_hi(b.y);
        qf[12]= bf2f_lo(b.z);  qf[13]= bf2f_hi(b.z);  qf[14] = bf2f_lo(b.w);  qf[15] = bf2f_hi(b.w);
    }

    float s = 0.f;
    float acc[16];
    #pragma unroll
    for (int d = 0; d < 16; ++d) acc[d] = 0.f;

    int start = roff[i];
    int end   = start + cnt[i];
    for (int p = start + j; p < end; p += 8) {
        int c = ecol[p];
        const uint4* kp = (const uint4*)(kv + (size_t)c * 256 + hh * 32);
        uint4 ka = kp[0], kb = kp[1];   // k fragment (32B)
        uint4 va = kp[2], vb = kp[3];   // v fragment (32B), same 64B line
        float dot;
        dot = qf[0] * bf2f_lo(ka.x);
        dot = fmaf(qf[1],  bf2f_hi(ka.x), dot); dot = fmaf(qf[2],  bf2f_lo(ka.y), dot);
        dot = fmaf(qf[3],  bf2f_hi(ka.y), dot); dot = fmaf(qf[4],  bf2f_lo(ka.z), dot);
        dot = fmaf(qf[5],  bf2f_hi(ka.z), dot); dot = fmaf(qf[6],  bf2f_lo(ka.w), dot);
        dot = fmaf(qf[7],  bf2f_hi(ka.w), dot); dot = fmaf(qf[8],  bf2f_lo(kb.x), dot);
        dot = fmaf(qf[9],  bf2f_hi(kb.x), dot); dot = fmaf(qf[10], bf2f_lo(kb.y), dot);
        dot = fmaf(qf[11], bf2f_hi(kb.y), dot); dot = fmaf(qf[12], bf2f_lo(kb.z), dot);
        dot = fmaf(qf[13], bf2f_hi(kb.z), dot); dot = fmaf(qf[14], bf2f_lo(kb.w), dot);
        dot = fmaf(qf[15], bf2f_hi(kb.w), dot);
        float ev = __expf(dot);
        s += ev;
        acc[0]  = fmaf(ev, bf2f_lo(va.x), acc[0]);  acc[1]  = fmaf(ev, bf2f_hi(va.x), acc[1]);
        acc[2]  = fmaf(ev, bf2f_lo(va.y), acc[2]);  acc[3]  = fmaf(ev, bf2f_hi(va.y), acc[3]);
        acc[4]  = fmaf(ev, bf2f_lo(va.z), acc[4]);  acc[5]  = fmaf(ev, bf2f_hi(va.z), acc[5]);
        acc[6]  = fmaf(ev, bf2f_lo(va.w), acc[6]);  acc[7]  = fmaf(ev, bf2f_hi(va.w), acc[7]);
        acc[8]  = fmaf(ev, bf2f_lo(vb.x), acc[8]);  acc[9]  = fmaf(ev, bf2f_hi(vb.x), acc[9]);
        acc[10] = fmaf(ev, bf2f_lo(vb.y), acc[10]); acc[11] = fmaf(ev, bf2f_hi(vb.y), acc[11]);
        acc[12] = fmaf(ev, bf2f_lo(vb.z), acc[12]); acc[13] = fmaf(ev, bf2f_hi(vb.z), acc[13]);
        acc[14] = fmaf(ev, bf2f_lo(vb.w), acc[14]); acc[15] = fmaf(ev, bf2f_hi(vb.w), acc[15]);
    }

    #pragma unroll
    for (int m = 8; m <= 32; m <<= 1) {
        s += __shfl_xor(s, m);
        #pragma unroll
        for (int d = 0; d < 16; ++d) acc[d] += __shfl_xor(acc[d], m);
    }

    if (j == 0) {
        float inv = (s > 0.f) ? 1.f / s : 0.f;
        unsigned int w[8];
        #pragma unroll
        for (int d = 0; d < 8; ++d)
            w[d] = (unsigned int)f2bf(acc[2 * d] * inv) |
                   ((unsigned int)f2bf(acc[2 * d + 1] * inv) << 16);
        uint4* op = (uint4*)(ao + (size_t)i * 128 + hh * 16);
        op[0] = make_uint4(w[0], w[1], w[2], w[3]);
        op[1] = make_uint4(w[4], w[5], w[6], w[7]);
    }
}

// ---------------------------------------------------------------------------
// Output projection via bf16 MFMA, NO LDS: out = ao @ Wo^T + bo (fp32 out).
// Wo read from prepped global bf16 buffer (K-cols pre-permuted).
// ---------------------------------------------------------------------------
__global__ __launch_bounds__(256) void outproj_kernel(
    const unsigned short* __restrict__ ao, const unsigned short* __restrict__ wobf,
    const float* __restrict__ bo, float* __restrict__ out, int n)
{
    const int tid  = threadIdx.x;
    const int nb   = blockIdx.x * 64;
    const int wv   = tid >> 6;
    const int lane = tid & 63;
    const int jj   = lane & 15;
    const int g    = lane >> 4;

    const int node_a = nb + wv * 16 + jj;
    bf16x8 afrag[4];
    #pragma unroll
    for (int kk = 0; kk < 4; ++kk) {
        if (node_a < n)
            afrag[kk] = *(const bf16x8*)(ao + (size_t)node_a * 128 + kk * 32 + g * 8);
        else {
            bf16x8 z;
            #pragma unroll
            for (int i = 0; i < 8; ++i) z[i] = 0;
            afrag[kk] = z;
        }
    }

    f32x4 acc[8];
    #pragma unroll
    for (int ct = 0; ct < 8; ++ct) { f32x4 z = {0.f, 0.f, 0.f, 0.f}; acc[ct] = z; }

    #pragma unroll
    for (int kk = 0; kk < 4; ++kk) {
        #pragma unroll
        for (int ct = 0; ct < 8; ++ct) {
            bf16x8 b = *(const bf16x8*)(wobf + (ct * 16 + jj) * 128 + kk * 32 + g * 8);
            acc[ct] = __builtin_amdgcn_mfma_f32_16x16x32_bf16(afrag[kk], b, acc[ct], 0, 0, 0);
        }
    }

    #pragma unroll
    for (int ct = 0; ct < 8; ++ct) {
        int jr = ct * 16 + jj;
        float bsv = bo[jr];
        #pragma unroll
        for (int r = 0; r < 4; ++r) {
            int node = nb + wv * 16 + g * 4 + r;
            if (node < n)
                out[(size_t)node * 128 + jr] = acc[ct][r] + bsv;
        }
    }
}

// ---------------------------------------------------------------------------

extern "C" void kernel_launch(void* const* d_in, const int* in_sizes, int n_in,
                              void* d_out, int out_size, void* d_ws, size_t ws_size,
                              hipStream_t stream)
{
    const float* h   = (const float*)d_in[0];
    const int*   row = (const int*)d_in[1];
    const int*   col = (const int*)d_in[2];
    const float* Wq  = (const float*)d_in[3];
    const float* bq  = (const float*)d_in[4];
    const float* Wk  = (const float*)d_in[5];
    const float* bk  = (const float*)d_in[6];
    const float* Wv  = (const float*)d_in[7];
    const float* bv  = (const float*)d_in[8];
    const float* Wo  = (const float*)d_in[9];
    const float* bo  = (const float*)d_in[10];

    const int n = in_sizes[0] / 128;
    const int E = in_sizes[1];
    float* out = (float*)d_out;

    // workspace layout
    char* ws = (char*)d_ws;
    unsigned short* q    = (unsigned short*)ws; ws += (size_t)n * 128 * sizeof(unsigned short);
    unsigned short* kv   = (unsigned short*)ws; ws += (size_t)n * 256 * sizeof(unsigned short);
    unsigned short* wbf  = (unsigned short*)ws; ws += (size_t)3 * 16384 * sizeof(unsigned short);
    unsigned short* wobf = (unsigned short*)ws; ws += (size_t)16384 * sizeof(unsigned short);
    float* bp = (float*)ws; ws += 384 * sizeof(float);
    int* cnt  = (int*)ws; ws += (size_t)n * sizeof(int);
    int* roff = (int*)ws; ws += (size_t)n * sizeof(int);
    int* cur  = (int*)ws; ws += (size_t)n * sizeof(int);
    int* ecol = (int*)ws; ws += (size_t)E * sizeof(int);
    int* btot = (int*)ws; ws += 256 * sizeof(int);
    unsigned short* ao = q;   // alias: attn reads q[i] into regs before storing ao[i]
    if (ws_size < (size_t)(ws - (char*)d_ws)) return;

    (void)hipMemsetAsync(cnt, 0, (size_t)n * sizeof(int), stream);

    prep_kernel<<<257, 256, 0, stream>>>(Wq, Wk, Wv, Wo, bq, bk, bv, wbf, wobf, bp);

    const int projBlocks = (n + 63) / 64;
    const long totalT = (long)projBlocks * TPB;
    const int ept = (int)((E + totalT - 1) / totalT);
    proj_kernel<<<projBlocks, TPB, 0, stream>>>(h, wbf, bp, q, kv, n, row, cnt, E, ept);

    int nsb = (n + SCAN_E - 1) / SCAN_E;   // 49 for n=100k (<= 256)
    scan1_kernel<<<nsb, SCAN_T, 0, stream>>>(cnt, roff, btot, n);
    scan2_kernel<<<1, SCAN_T, 0, stream>>>(btot, nsb);
    scan3_kernel<<<nsb, SCAN_T, 0, stream>>>(roff, cur, btot, n);

    int scBlocks = (E + TPB * EDGE_B - 1) / (TPB * EDGE_B);
    scatter_kernel<<<scBlocks, TPB, 0, stream>>>(row, col, cur, ecol, E);

    attn_kernel<<<(n + 3) / 4, TPB, 0, stream>>>(q, kv, roff, cnt, ecol, ao, n);

    outproj_kernel<<<(n + 63) / 64, TPB, 0, stream>>>(ao, wobf, bo, out, n);
}